// Round 6
// baseline (188.398 us; speedup 1.0000x reference)
//
#include <hip/hip_runtime.h>

// SupConLoss, B=4096 D=256 L=20, T=0.07.
// lv_il = lp_i + m_i - masked_mean_il ; lp_i = log(expsum_i*e^{ci-m} + 1e-20)
// masked_sum via factorization: dot(F_i, Wt[5l+v]) - c_i, Wt = sum_j F_j onehot(lab_j), fp32.
// No intermediate bulk tensors: k_main reads only pristine F (fp32->bf16 on the fly).

#define B_N 4096
#define D_K 256
#define L_N 20
#define INVT 14.285714285714286f

// ws layout (bytes)
#define C_OFF    0x000000u  // f32 [4096]      c_i = S_ii
#define CNT_OFF  0x004000u  // int [20][5]
#define WT_OFF   0x010000u  // f32 [100][256]  atomic-accumulated (memset 0)
#define ACC_OFF  0x029000u  // f32 Ls[20], Ss[20] (memset 0)
#define MPT_OFF  0x030000u  // f32 [64][4096]  row-max partials, col-major
#define EPT_OFF  0x130000u  // f32 [64][4096]  expsum partials, col-major

typedef __bf16 bf16x8 __attribute__((ext_vector_type(8)));
typedef float f32x4 __attribute__((ext_vector_type(4)));

struct __align__(16) U4 { unsigned int x, y, z, w; };

__device__ __forceinline__ unsigned int f2bf(float x) {
  unsigned int u = __float_as_uint(x);
  return (u + 0x7FFFu + ((u >> 16) & 1u)) >> 16;  // RNE
}

__device__ __forceinline__ U4 pack8(float4 a, float4 b) {
  U4 r;
  r.x = f2bf(a.x) | (f2bf(a.y) << 16);
  r.y = f2bf(a.z) | (f2bf(a.w) << 16);
  r.z = f2bf(b.x) | (f2bf(b.y) << 16);
  r.w = f2bf(b.z) | (f2bf(b.w) << 16);
  return r;
}

// ---------------- prep: rowsumsq | label counts | Wt atomic build ----------------
__global__ __launch_bounds__(256) void k_prep(const float* __restrict__ F,
                                              const int* __restrict__ lab,
                                              unsigned char* __restrict__ ws) {
  __shared__ int sc[4][5];
  __shared__ int slab[256];
  const int bid = blockIdx.x, t = threadIdx.x;
  if (bid < 1024) {
    const int w = t >> 6, l = t & 63;
    const int row = bid * 4 + w;
    float4 v = *(const float4*)(F + row * 256 + l * 4);
    float ss = v.x * v.x + v.y * v.y + v.z * v.z + v.w * v.w;
    #pragma unroll
    for (int off = 1; off < 64; off <<= 1) ss += __shfl_xor(ss, off, 64);
    if (l == 0) ((float*)(ws + C_OFF))[row] = ss * INVT;
  } else if (bid < 1044) {
    const int l = bid - 1024;
    int c0 = 0, c1 = 0, c2 = 0, c3 = 0, c4 = 0;
    for (int j = t; j < B_N; j += 256) {
      int v = lab[j * L_N + l];
      c0 += (v == 0); c1 += (v == 1); c2 += (v == 2); c3 += (v == 3); c4 += (v == 4);
    }
    #pragma unroll
    for (int off = 1; off < 64; off <<= 1) {
      c0 += __shfl_xor(c0, off, 64); c1 += __shfl_xor(c1, off, 64);
      c2 += __shfl_xor(c2, off, 64); c3 += __shfl_xor(c3, off, 64);
      c4 += __shfl_xor(c4, off, 64);
    }
    const int w = t >> 6;
    if ((t & 63) == 0) { sc[w][0] = c0; sc[w][1] = c1; sc[w][2] = c2; sc[w][3] = c3; sc[w][4] = c4; }
    __syncthreads();
    if (t < 5) ((int*)(ws + CNT_OFF))[l * 5 + t] = sc[0][t] + sc[1][t] + sc[2][t] + sc[3][t];
  } else {
    // Wt[5l+v][d] += F[j][d] over a 256-j chunk: register accumulate + 5 atomics
    const int idx = bid - 1044;          // 0..319
    const int l = idx >> 4, chunk = idx & 15;
    const int j0 = chunk * 256;
    slab[t] = lab[(j0 + t) * L_N + l];
    __syncthreads();
    const int d = t;
    float a0 = 0, a1 = 0, a2 = 0, a3 = 0, a4 = 0;
    #pragma unroll 16
    for (int jj = 0; jj < 256; ++jj) {
      const int v = slab[jj];
      const float x = F[(j0 + jj) * 256 + d];
      a0 += (v == 0) ? x : 0.f;
      a1 += (v == 1) ? x : 0.f;
      a2 += (v == 2) ? x : 0.f;
      a3 += (v == 3) ? x : 0.f;
      a4 += (v == 4) ? x : 0.f;
    }
    float* Wt = (float*)(ws + WT_OFF);
    atomicAdd(Wt + (l * 5 + 0) * 256 + d, a0);
    atomicAdd(Wt + (l * 5 + 1) * 256 + d, a1);
    atomicAdd(Wt + (l * 5 + 2) * 256 + d, a2);
    atomicAdd(Wt + (l * 5 + 3) * 256 + d, a3);
    atomicAdd(Wt + (l * 5 + 4) * 256 + d, a4);
  }
}

// ---------------- main: fused F@F^T row-reduce GEMM, reads pristine fp32 F only ----------------
__global__ __launch_bounds__(512, 2) void k_main(const float* __restrict__ F,
                                                 unsigned char* __restrict__ ws) {
  __shared__ unsigned char smem[65536 + 8192];  // B-panel bf16 swizzled + epilogue scratch
  const int bid = blockIdx.x, t = threadIdx.x;
  const int w = t >> 6, l = t & 63;
  const int lr = l & 15, lg = l >> 4;
  // 2-D XCD partition (perf-only)
  const int r = bid & 7, s = bid >> 3;
  const int bm = ((r & 3) << 1) | (s & 1);
  const int bn = ((r >> 2) << 4) | (s >> 1);
  const int rowbase = bm * 512 + w * 64;
  const int colb = bn * 128;
  // stage B-panel rows [colb..colb+128): fp32 -> bf16 -> swizzled LDS
  {
    const int srow = t >> 2, q = t & 3;
    const float* src = F + (colb + srow) * 256 + q * 64;
    #pragma unroll
    for (int i = 0; i < 8; ++i) {
      float4 f0 = *(const float4*)(src + i * 8);
      float4 f1 = *(const float4*)(src + i * 8 + 4);
      const int kb = q * 128 + i * 16;
      *(U4*)(smem + srow * 512 + (kb ^ ((srow & 7) << 4))) = pack8(f0, f1);
    }
  }
  __syncthreads();
  const float* cvec = (const float*)(ws + C_OFF);
  float* MPT = (float*)(ws + MPT_OFF);
  float* EPT = (float*)(ws + EPT_OFF);
  const float* arow0 = F + (rowbase + lr) * 256 + lg * 8;  // A base for this lane
  #pragma unroll 1
  for (int tile = 0; tile < 2; ++tile) {
    f32x4 acc[4][4] = {};
    #pragma unroll 1
    for (int kk = 0; kk < 8; ++kk) {
      bf16x8 afr[4];
      #pragma unroll
      for (int mi = 0; mi < 4; ++mi) {
        const float* ap = arow0 + mi * 16 * 256 + kk * 32;
        float4 a0 = *(const float4*)(ap);
        float4 a1 = *(const float4*)(ap + 4);
        afr[mi] = __builtin_bit_cast(bf16x8, pack8(a0, a1));
      }
      bf16x8 bfr[4];
      #pragma unroll
      for (int n = 0; n < 4; ++n) {
        const int brow = tile * 64 + n * 16 + lr;
        const int kb = kk * 64 + lg * 16;
        bfr[n] = __builtin_bit_cast(bf16x8,
            *(const U4*)(smem + brow * 512 + (kb ^ ((brow & 7) << 4))));
      }
      #pragma unroll
      for (int mi = 0; mi < 4; ++mi)
        #pragma unroll
        for (int n = 0; n < 4; ++n)
          acc[mi][n] = __builtin_amdgcn_mfma_f32_16x16x32_bf16(afr[mi], bfr[n], acc[mi][n], 0, 0, 0);
    }
    float2* scr = (float2*)(smem + 65536 + (w * 2 + tile) * 512);
    #pragma unroll
    for (int mi = 0; mi < 4; ++mi) {
      #pragma unroll
      for (int rr = 0; rr < 4; ++rr) {
        const int row = rowbase + mi * 16 + lg * 4 + rr;
        const float crow = cvec[row];
        float vm = -3.4e38f, es = 0.f;
        #pragma unroll
        for (int n = 0; n < 4; ++n) {
          const int col = colb + tile * 64 + n * 16 + lr;
          const float v = acc[mi][n][rr] * INVT;
          vm = fmaxf(vm, v);
          const float e = __expf(v - crow);
          es += (col == row) ? 0.f : e;  // exclude diagonal from expsum
        }
        #pragma unroll
        for (int off = 1; off < 16; off <<= 1) {
          vm = fmaxf(vm, __shfl_xor(vm, off, 16));
          es += __shfl_xor(es, off, 16);
        }
        if (lr == 0) scr[mi * 16 + lg * 4 + rr] = make_float2(vm, es);
      }
    }
    const float2 v2 = scr[l];
    const int c2 = (colb >> 6) + tile;
    MPT[c2 * 4096 + rowbase + l] = v2.x;
    EPT[c2 * 4096 + rowbase + l] = v2.y;
  }
}

// ---------------- final: per-row loss; wave-per-row, Wt dots from LDS ----------------
__global__ __launch_bounds__(1024) void k_final(const float* __restrict__ F,
                                                const int* __restrict__ lab,
                                                unsigned char* __restrict__ ws) {
  __shared__ float WtL[25600];
  __shared__ float sL[16][20], sS[16][20];
  const int t = threadIdx.x, w = t >> 6, l = t & 63;
  const float* Wt = (const float*)(ws + WT_OFF);
  for (int s4 = t; s4 < 6400; s4 += 1024)
    *(float4*)(WtL + s4 * 4) = *(const float4*)(Wt + s4 * 4);
  __syncthreads();
  const int i = blockIdx.x * 16 + w;
  const float* MPT = (const float*)(ws + MPT_OFF);
  const float* EPT = (const float*)(ws + EPT_OFF);
  float m = MPT[l * 4096 + i];
  float e = EPT[l * 4096 + i];
  #pragma unroll
  for (int off = 1; off < 64; off <<= 1) {
    m = fmaxf(m, __shfl_xor(m, off, 64));
    e += __shfl_xor(e, off, 64);
  }
  const float ci = ((const float*)(ws + C_OFF))[i];
  const float lp = logf(e * __expf(ci - m) + 1e-20f);
  const float4 Ff = *(const float4*)(F + i * 256 + l * 4);
  const int* cnts = (const int*)(ws + CNT_OFF);
  for (int ll = 0; ll < 20; ++ll) {
    const int v = lab[i * 20 + ll];
    const int cnt = cnts[ll * 5 + v] - 1;  // exclude self
    float lv = 0.f, sg = 0.f;
    if (cnt > 0) {
      const float4 Wf = *(const float4*)(WtL + (ll * 5 + v) * 256 + l * 4);
      float p = Ff.x * Wf.x + Ff.y * Wf.y + Ff.z * Wf.z + Ff.w * Wf.w;
      #pragma unroll
      for (int off = 1; off < 64; off <<= 1) p += __shfl_xor(p, off, 64);
      const float me = p * INVT - ci;  // masked sum excl self, S units
      lv = lp - (me - (float)cnt * m) / (float)cnt;
    } else {
      sg = 1.f;
    }
    if (l == 0) { sL[w][ll] = lv; sS[w][ll] = sg; }
  }
  __syncthreads();
  if (t < 20) {
    float Lsum = 0.f, Ssum = 0.f;
    #pragma unroll
    for (int ww = 0; ww < 16; ++ww) { Lsum += sL[ww][t]; Ssum += sS[ww][t]; }
    float* ACC = (float*)(ws + ACC_OFF);
    atomicAdd(ACC + t, Lsum);
    atomicAdd(ACC + 20 + t, Ssum);
  }
}

// ---------------- final scalar ----------------
__global__ void k_out(unsigned char* __restrict__ ws, float* __restrict__ out) {
  const int t = threadIdx.x;  // 64
  float v = 0.f;
  if (t < 20) {
    const float* ACC = (const float*)(ws + ACC_OFF);
    v = ACC[t] / (4096.f - ACC[20 + t]);
  }
  #pragma unroll
  for (int off = 1; off < 64; off <<= 1) v += __shfl_xor(v, off, 64);
  if (t == 0) out[0] = v * 0.05f;
}

extern "C" void kernel_launch(void* const* d_in, const int* in_sizes, int n_in,
                              void* d_out, int out_size, void* d_ws, size_t ws_size,
                              hipStream_t stream) {
  const float* F = (const float*)d_in[0];
  const int* lab = (const int*)d_in[1];
  unsigned char* ws = (unsigned char*)d_ws;
  float* out = (float*)d_out;
  hipMemsetAsync(ws + WT_OFF, 0, 102400 + 256, stream);  // zero Wt + ACC
  k_prep<<<1364, 256, 0, stream>>>(F, lab, ws);          // 1024 sumsq + 20 counts + 320 Wt
  k_main<<<256, 512, 0, stream>>>(F, ws);                // F@F^T row-reduce
  k_final<<<256, 1024, 0, stream>>>(F, lab, ws);
  k_out<<<1, 64, 0, stream>>>(ws, out);
}

// Round 7
// 138.174 us; speedup vs baseline: 1.3635x; 1.3635x over previous
//
#include <hip/hip_runtime.h>

// SupConLoss, B=4096 D=256 L=20, T=0.07.
// lv_il = lp_i + m_i - masked_mean_il ; lp_i = log(expsum_i*e^{ci-m} + 1e-20)
// masked_sum via factorization: dot(F_i, Wt[5l+v]) - c_i, Wt = sum_j F_j onehot(lab_j), fp32.
// 3 dispatches: memset | fused{GEMM+rowreduce, counts, Wt} | final{per-row loss + scalar}.

#define B_N 4096
#define D_K 256
#define L_N 20
#define INVT 14.285714285714286f

// ws layout (bytes)
#define CNT_OFF  0x004000u  // int [20][5]
#define WT_OFF   0x010000u  // f32 [100][256] atomic-accumulated (memset 0)
#define ACC_OFF  0x029000u  // f32 Ls[20], Ss[20], u32 done-counter @+160 (memset 0)
#define MPT_OFF  0x030000u  // f32 [64][4096] row-max partials, col-major
#define EPT_OFF  0x130000u  // f32 [64][4096] expsum partials, col-major

typedef __bf16 bf16x8 __attribute__((ext_vector_type(8)));
typedef float f32x4 __attribute__((ext_vector_type(4)));

struct __align__(16) U4 { unsigned int x, y, z, w; };

__device__ __forceinline__ unsigned int f2bf(float x) {
  unsigned int u = __float_as_uint(x);
  return (u + 0x7FFFu + ((u >> 16) & 1u)) >> 16;  // RNE
}

__device__ __forceinline__ U4 pack8(float4 a, float4 b) {
  U4 r;
  r.x = f2bf(a.x) | (f2bf(a.y) << 16);
  r.y = f2bf(a.z) | (f2bf(a.w) << 16);
  r.z = f2bf(b.x) | (f2bf(b.y) << 16);
  r.w = f2bf(b.z) | (f2bf(b.w) << 16);
  return r;
}

// ---------------- fused: F@F^T row-reduce GEMM (0..255) | counts (256..275) | Wt (276..435) --------
__global__ __launch_bounds__(512, 2) void k_fused(const float* __restrict__ F,
                                                  const int* __restrict__ lab,
                                                  unsigned char* __restrict__ ws) {
  __shared__ unsigned char smem[75776];  // 64K B-panel | 8K epilogue scratch | 2K scvec
  const int bid = blockIdx.x, t = threadIdx.x;
  if (bid < 256) {
    const int w = t >> 6, l = t & 63;
    const int lr = l & 15, lg = l >> 4;
    // 2-D XCD partition (perf-only)
    const int r = bid & 7, s = bid >> 3;
    const int bm = ((r & 3) << 1) | (s & 1);
    const int bn = ((r >> 2) << 4) | (s >> 1);
    const int rowbase = bm * 512 + w * 64;
    const int colb = bn * 128;
    // stage B-panel rows [colb..colb+128): fp32 -> bf16 -> swizzled LDS
    {
      const int srow = t >> 2, q = t & 3;
      const float* src = F + (colb + srow) * 256 + q * 64;
      #pragma unroll
      for (int i = 0; i < 8; ++i) {
        float4 f0 = *(const float4*)(src + i * 8);
        float4 f1 = *(const float4*)(src + i * 8 + 4);
        const int kb = q * 128 + i * 16;
        *(U4*)(smem + srow * 512 + (kb ^ ((srow & 7) << 4))) = pack8(f0, f1);
      }
    }
    __syncthreads();
    float* MPT = (float*)(ws + MPT_OFF);
    float* EPT = (float*)(ws + EPT_OFF);
    float* scv = (float*)(smem + 73728);       // [8 waves][64 rows] c_i for own rows
    const float* arow0 = F + (rowbase + lr) * 256 + lg * 8;
    float ssq[4] = {0.f, 0.f, 0.f, 0.f};
    #pragma unroll 1
    for (int tile = 0; tile < 2; ++tile) {
      f32x4 acc[4][4] = {};
      #pragma unroll 1
      for (int kk = 0; kk < 8; ++kk) {
        bf16x8 afr[4];
        #pragma unroll
        for (int mi = 0; mi < 4; ++mi) {
          const float* ap = arow0 + mi * 16 * 256 + kk * 32;
          float4 a0 = *(const float4*)(ap);
          float4 a1 = *(const float4*)(ap + 4);
          if (tile == 0)
            ssq[mi] += a0.x * a0.x + a0.y * a0.y + a0.z * a0.z + a0.w * a0.w
                     + a1.x * a1.x + a1.y * a1.y + a1.z * a1.z + a1.w * a1.w;
          afr[mi] = __builtin_bit_cast(bf16x8, pack8(a0, a1));
        }
        bf16x8 bfr[4];
        #pragma unroll
        for (int n = 0; n < 4; ++n) {
          const int brow = tile * 64 + n * 16 + lr;
          const int kb = kk * 64 + lg * 16;
          bfr[n] = __builtin_bit_cast(bf16x8,
              *(const U4*)(smem + brow * 512 + (kb ^ ((brow & 7) << 4))));
        }
        #pragma unroll
        for (int mi = 0; mi < 4; ++mi)
          #pragma unroll
          for (int n = 0; n < 4; ++n)
            acc[mi][n] = __builtin_amdgcn_mfma_f32_16x16x32_bf16(afr[mi], bfr[n], acc[mi][n], 0, 0, 0);
      }
      if (tile == 0) {
        // finish per-row sumsq: lanes {lr, lr+16, lr+32, lr+48} hold partials of row mi*16+lr
        #pragma unroll
        for (int mi = 0; mi < 4; ++mi) {
          float ss = ssq[mi];
          ss += __shfl_xor(ss, 16, 64);
          ss += __shfl_xor(ss, 32, 64);
          if (lg == 0) scv[w * 64 + mi * 16 + lr] = ss * INVT;
        }
      }
      float2* scr = (float2*)(smem + 65536 + (w * 2 + tile) * 512);
      #pragma unroll
      for (int mi = 0; mi < 4; ++mi) {
        #pragma unroll
        for (int rr = 0; rr < 4; ++rr) {
          const int row = rowbase + mi * 16 + lg * 4 + rr;
          const float crow = scv[w * 64 + mi * 16 + lg * 4 + rr];
          float vm = -3.4e38f, es = 0.f;
          #pragma unroll
          for (int n = 0; n < 4; ++n) {
            const int col = colb + tile * 64 + n * 16 + lr;
            const float v = acc[mi][n][rr] * INVT;
            vm = fmaxf(vm, v);
            const float e = __expf(v - crow);
            es += (col == row) ? 0.f : e;  // exclude diagonal from expsum
          }
          #pragma unroll
          for (int off = 1; off < 16; off <<= 1) {
            vm = fmaxf(vm, __shfl_xor(vm, off, 16));
            es += __shfl_xor(es, off, 16);
          }
          if (lr == 0) scr[mi * 16 + lg * 4 + rr] = make_float2(vm, es);
        }
      }
      const float2 v2 = scr[l];
      const int c2 = (colb >> 6) + tile;
      MPT[c2 * 4096 + rowbase + l] = v2.x;
      EPT[c2 * 4096 + rowbase + l] = v2.y;
    }
  } else if (bid < 276) {
    // counts[l][v], 512 threads
    __shared__ int sc[8][5];
    const int l = bid - 256;
    int c0 = 0, c1 = 0, c2 = 0, c3 = 0, c4 = 0;
    for (int j = t; j < B_N; j += 512) {
      int v = lab[j * L_N + l];
      c0 += (v == 0); c1 += (v == 1); c2 += (v == 2); c3 += (v == 3); c4 += (v == 4);
    }
    #pragma unroll
    for (int off = 1; off < 64; off <<= 1) {
      c0 += __shfl_xor(c0, off, 64); c1 += __shfl_xor(c1, off, 64);
      c2 += __shfl_xor(c2, off, 64); c3 += __shfl_xor(c3, off, 64);
      c4 += __shfl_xor(c4, off, 64);
    }
    const int w = t >> 6;
    if ((t & 63) == 0) { sc[w][0] = c0; sc[w][1] = c1; sc[w][2] = c2; sc[w][3] = c3; sc[w][4] = c4; }
    __syncthreads();
    if (t < 5) {
      int s5 = 0;
      #pragma unroll
      for (int ww = 0; ww < 8; ++ww) s5 += sc[ww][t];
      ((int*)(ws + CNT_OFF))[l * 5 + t] = s5;
    }
  } else {
    // Wt[5l+v][d] += F[j][d] over a 512-j block (two 256-halves), reg accumulate + 5 atomics
    int* slab = (int*)smem;
    const int idx = bid - 276;           // 0..159
    const int l = idx >> 3, jblk = idx & 7;
    const int j0 = jblk * 512;
    slab[t] = lab[(j0 + t) * L_N + l];
    __syncthreads();
    const int d = t & 255, half = t >> 8;
    const int base = half * 256;
    float a0 = 0, a1 = 0, a2 = 0, a3 = 0, a4 = 0;
    #pragma unroll 16
    for (int jj = 0; jj < 256; ++jj) {
      const int v = slab[base + jj];
      const float x = F[(j0 + base + jj) * 256 + d];
      a0 += (v == 0) ? x : 0.f;
      a1 += (v == 1) ? x : 0.f;
      a2 += (v == 2) ? x : 0.f;
      a3 += (v == 3) ? x : 0.f;
      a4 += (v == 4) ? x : 0.f;
    }
    float* Wt = (float*)(ws + WT_OFF);
    atomicAdd(Wt + (l * 5 + 0) * 256 + d, a0);
    atomicAdd(Wt + (l * 5 + 1) * 256 + d, a1);
    atomicAdd(Wt + (l * 5 + 2) * 256 + d, a2);
    atomicAdd(Wt + (l * 5 + 3) * 256 + d, a3);
    atomicAdd(Wt + (l * 5 + 4) * 256 + d, a4);
  }
}

// ---------------- final: per-row loss (wave-per-row) + last-block scalar ----------------
__global__ __launch_bounds__(1024) void k_final(const float* __restrict__ F,
                                                const int* __restrict__ lab,
                                                unsigned char* __restrict__ ws,
                                                float* __restrict__ out) {
  __shared__ float WtL[25600];
  __shared__ float sL[16][20], sS[16][20];
  const int t = threadIdx.x, w = t >> 6, l = t & 63;
  const float* Wt = (const float*)(ws + WT_OFF);
  for (int s4 = t; s4 < 6400; s4 += 1024)
    *(float4*)(WtL + s4 * 4) = *(const float4*)(Wt + s4 * 4);
  __syncthreads();
  const int i = blockIdx.x * 16 + w;
  const float* MPT = (const float*)(ws + MPT_OFF);
  const float* EPT = (const float*)(ws + EPT_OFF);
  float m = MPT[l * 4096 + i];
  float e = EPT[l * 4096 + i];
  const float4 Ff = *(const float4*)(F + i * 256 + l * 4);
  float ci = Ff.x * Ff.x + Ff.y * Ff.y + Ff.z * Ff.z + Ff.w * Ff.w;
  #pragma unroll
  for (int off = 1; off < 64; off <<= 1) {
    m = fmaxf(m, __shfl_xor(m, off, 64));
    e += __shfl_xor(e, off, 64);
    ci += __shfl_xor(ci, off, 64);
  }
  ci *= INVT;
  const float lp = logf(e * __expf(ci - m) + 1e-20f);
  const int* cnts = (const int*)(ws + CNT_OFF);
  for (int ll = 0; ll < 20; ++ll) {
    const int v = lab[i * 20 + ll];
    const int cnt = cnts[ll * 5 + v] - 1;  // exclude self
    float lv = 0.f, sg = 0.f;
    if (cnt > 0) {
      const float4 Wf = *(const float4*)(WtL + (ll * 5 + v) * 256 + l * 4);
      float p = Ff.x * Wf.x + Ff.y * Wf.y + Ff.z * Wf.z + Ff.w * Wf.w;
      #pragma unroll
      for (int off = 1; off < 64; off <<= 1) p += __shfl_xor(p, off, 64);
      const float me = p * INVT - ci;  // masked sum excl self, S units
      lv = lp - (me - (float)cnt * m) / (float)cnt;
    } else {
      sg = 1.f;
    }
    if (l == 0) { sL[w][ll] = lv; sS[w][ll] = sg; }
  }
  __syncthreads();
  float* ACC = (float*)(ws + ACC_OFF);
  if (t < 20) {
    float Lsum = 0.f, Ssum = 0.f;
    #pragma unroll
    for (int ww = 0; ww < 16; ++ww) { Lsum += sL[ww][t]; Ssum += sS[ww][t]; }
    atomicAdd(ACC + t, Lsum);
    atomicAdd(ACC + 20 + t, Ssum);
  }
  __syncthreads();
  if (t == 0) {
    __threadfence();
    unsigned int done = atomicAdd((unsigned int*)(ws + ACC_OFF + 160), 1u);
    if (done == 255) {  // last block: final scalar
      float v = 0.f;
      #pragma unroll
      for (int ll = 0; ll < 20; ++ll) {
        float Ls = __hip_atomic_load(ACC + ll, __ATOMIC_RELAXED, __HIP_MEMORY_SCOPE_AGENT);
        float Ss = __hip_atomic_load(ACC + 20 + ll, __ATOMIC_RELAXED, __HIP_MEMORY_SCOPE_AGENT);
        v += Ls / (4096.f - Ss);
      }
      out[0] = v * 0.05f;
    }
  }
}

extern "C" void kernel_launch(void* const* d_in, const int* in_sizes, int n_in,
                              void* d_out, int out_size, void* d_ws, size_t ws_size,
                              hipStream_t stream) {
  const float* F = (const float*)d_in[0];
  const int* lab = (const int*)d_in[1];
  unsigned char* ws = (unsigned char*)d_ws;
  float* out = (float*)d_out;
  hipMemsetAsync(ws + WT_OFF, 0, 102400 + 256, stream);  // zero Wt + ACC + done-counter
  k_fused<<<436, 512, 0, stream>>>(F, lab, ws);          // 256 GEMM + 20 counts + 160 Wt
  k_final<<<256, 1024, 0, stream>>>(F, lab, ws, out);
}